// Round 6
// baseline (63.219 us; speedup 1.0000x reference)
//
#include <hip/hip_runtime.h>
#include <hip/hip_bf16.h>

// SConv2dAvg: stride-2 conv with per-output-pixel stochastic tap selection.
// B=32 C=128 H=W=64, O=256 kh=kw=3, oh=ow=32, PAD=1, STRIDE=2.
//
// Plan:
//  1) prep (fused): weight fp32 -> bf16 wpre[36][256][32] (K = tap*128+c,
//     K-step 32, 2-bit XOR swizzle baked), and input NCHW fp32 -> bf16 padded
//     NHWC tp[32][66][66][128] (zero halo -> no bounds checks in main loop).
//  2) sconv_mfma6: implicit GEMM 128o x 128pix, 8 waves of 64o x 32pix
//     (R4 wave count: 16 waves/CU — R5 showed 8/CU is latency-bound).
//     A (pixels) DIRECT global->VGPR with register double-buffer (no LDS);
//     B (weights) via global_load_lds, 4 buffers, counted vmcnt, 1 barrier
//     per step (T3/T4), setprio (T5), XCD-chunked block swizzle (T1).

typedef short bf16x8 __attribute__((ext_vector_type(8)));
typedef float f32x4  __attribute__((ext_vector_type(4)));

#define NSTEP 36
#define WPRE_BYTES (NSTEP * 256 * 32 * 2)           // 589824
#define TRANS_BYTES (32 * 66 * 66 * 128 * 2)        // 35684352
#define TOTAL_WS (WPRE_BYTES + TRANS_BYTES)

__device__ __forceinline__ unsigned short f2bf(float x) {
  unsigned u = __float_as_uint(x);
  return (unsigned short)((u + 0x7fffu + ((u >> 16) & 1u)) >> 16);
}
__device__ __forceinline__ unsigned pk2(float a, float b) {
  unsigned ua = __float_as_uint(a), ub = __float_as_uint(b);
  return ((ua + 0x7fffu + ((ua >> 16) & 1u)) >> 16) |
         ((ub + 0x7fffu + ((ub >> 16) & 1u)) & 0xffff0000u);
}
__device__ __forceinline__ bf16x8 ld_frag(const uint4* a) {
  union { uint4 u; bf16x8 s; } cv; cv.u = *a; return cv.s;
}
__device__ __forceinline__ void async16(const void* g, void* l) {
  __builtin_amdgcn_global_load_lds(
      (__attribute__((address_space(1))) void*)(void*)g,
      (__attribute__((address_space(3))) void*)l, 16, 0, 0);
}

// ---------------- fused pre-pass: transform + wprep ------------------------
// grid (102, 32): x < 66 -> padded-NHWC transform of (row hp=x, batch y);
//                 x >= 66 -> wprep K-slice s = x-66, o-block = y (8 o's).
__global__ __launch_bounds__(256) void prep(const float* __restrict__ in,
                                            const float* __restrict__ w,
                                            unsigned short* __restrict__ tp,
                                            unsigned short* __restrict__ wpre) {
  const int tid = threadIdx.x;
  if (blockIdx.x >= 66) {   // ---- weight prep: wpre[s][o][32], swizzle baked
    const int s    = blockIdx.x - 66;       // 0..35
    const int o    = (blockIdx.y << 3) + (tid >> 5);
    const int k_in = tid & 31;
    const int kg   = (s << 5) + (((k_in >> 3) ^ ((o >> 1) & 3)) << 3) + (k_in & 7);
    const int tap  = kg >> 7;
    const int c    = kg & 127;
    const int di   = (tap >= 6) ? 2 : ((tap >= 3) ? 1 : 0);
    const int dj   = tap - di * 3;
    wpre[(s << 13) + (o << 5) + k_in] = f2bf(w[(o * 128 + c) * 9 + di * 3 + dj]);
    return;
  }
  // ---- input transform ----
  __shared__ float lds[128 * 65];
  const int hp = blockIdx.x;   // 0..65 padded row
  const int b  = blockIdx.y;
  uint4* rowp = (uint4*)(tp + (size_t)(b * 66 + hp) * 66 * 128);
  uint4 z; z.x = z.y = z.z = z.w = 0u;
  if (hp == 0 || hp == 65) {                 // zero border rows
    for (int s = tid; s < 1056; s += 256) rowp[s] = z;
    return;
  }
  const int h = hp - 1;
  const float* src = in + ((size_t)b << 19) + (h << 6);
  const int ww4 = (tid & 15) << 2;
  const int c0  = tid >> 4;
#pragma unroll
  for (int pass = 0; pass < 8; ++pass) {
    int c = (pass << 4) + c0;
    float4 v = *(const float4*)(src + ((size_t)c << 12) + ww4);  // coalesced
    float* lp = lds + c * 65 + ww4;
    lp[0] = v.x; lp[1] = v.y; lp[2] = v.z; lp[3] = v.w;
  }
  __syncthreads();
  for (int s = tid; s < 1056; s += 256) {
    if (s < 16 || s >= 1040) { rowp[s] = z; continue; }   // zero border cols
    int idx = s - 16;
    int wq = idx >> 4, c8 = idx & 15;
    const float* lp = lds + (c8 << 3) * 65 + wq;
    uint4 d;
    d.x = pk2(lp[0],   lp[65]);
    d.y = pk2(lp[130], lp[195]);
    d.z = pk2(lp[260], lp[325]);
    d.w = pk2(lp[390], lp[455]);
    rowp[s] = d;
  }
}

// ----------------------------- main kernel ---------------------------------
// grid 512 (XCD-chunked), 512 threads / 8 waves (2 o-waves x 4 p-groups).
// K-step 32. B (weights) in LDS: 4 buffers x 8KB, 2-3 deep prefetch, one
// barrier/step, vmcnt(6) counted. A (pixels) direct global->reg, dbuf FPa/FPb.
__global__ __launch_bounds__(512, 4) void sconv_mfma6(
    const unsigned short* __restrict__ tp,   // [32][66][66][128] bf16 padded
    const unsigned short* __restrict__ wpre, // [36][256][32] bf16 pre-swizzled
    const float* __restrict__ bias,
    const int* __restrict__ selh,            // [32][32]
    const int* __restrict__ selw,            // [32][32]
    float* __restrict__ out)                 // [32][256][32][32]
{
  __shared__ uint4 Blds[4][512];   // weights [o_local(128)][4 chunks], swz baked
  __shared__ float bias_s[128];

  const int tid = threadIdx.x;
  // XCD-chunked swizzle (T1): 512 = 8 XCDs x 64 consecutive logical tiles
  const int d0    = blockIdx.x;
  const int blk   = ((d0 & 7) << 6) + (d0 >> 3);
  const int b     = blk >> 4;
  const int y0    = ((blk >> 1) & 7) << 2;
  const int ohalf = blk & 1;

  if (tid < 128) bias_s[tid] = bias[(ohalf << 7) + tid];

  const int wv = tid >> 6, ln = tid & 63;
  const int wo = wv & 1;            // 2 o-waves x 64 o
  const int wp = wv >> 1;           // 4 p-groups x 32 pix
  const int lo = ln & 15, hi = ln >> 4;

  // ---- A-direct: lane (lo,hi) owns 16B chunk hi of pixels {P0,P1} k-rows
  size_t apix0, apix1;              // byte offset at tap(0,0), k-chunk hi
  {
#pragma unroll
    for (int f = 0; f < 2; ++f) {
      const int P  = (wp << 5) + (f << 4) + lo;
      const int py = y0 + (P >> 5);
      const int px = P & 31;
      const int addr = (b * 66 + 2 * py + selh[(py << 5) | px]) * 66
                     + 2 * px + selw[(py << 5) | px];
      const size_t v = ((size_t)addr << 8) + (hi << 4);
      if (f == 0) apix0 = v; else apix1 = v;
    }
  }
  const char* tbase = (const char*)tp;
  // B source: per-lane linear (swizzle baked in wpre)
  const char* wB = (const char*)wpre + (ohalf << 13) + (tid << 4);

  f32x4 acc[4][2] = {};             // [o-frag][pix-frag]

#define TOFF(KK) (((((KK) >> 2) >= 6 ? 2 : (((KK) >> 2) >= 3 ? 1 : 0)) * 66    \
                   + (((KK) >> 2) - 3 * (((KK) >> 2) >= 6 ? 2                  \
                                          : (((KK) >> 2) >= 3 ? 1 : 0)))) << 8)\
                  + (((KK) & 3) << 6)

#define LOADA(S0, S1, KK)                                                     \
  do {                                                                        \
    const int to_ = TOFF(KK);                                                 \
    S0 = *(const bf16x8*)(tbase + apix0 + to_);                               \
    S1 = *(const bf16x8*)(tbase + apix1 + to_);                               \
  } while (0)

#define STAGE_B(KK) async16(wB + ((KK) << 14), &Blds[(KK) & 3][tid >> 2 << 2]  \
                            + (tid & 3))

#define DO_MMA(BUF, S0, S1)                                                   \
  do {                                                                        \
    const uint4* B_ = &Blds[BUF][0];                                          \
    bf16x8 FW[4];                                                             \
    _Pragma("unroll")                                                         \
    for (int f = 0; f < 4; ++f) {                                             \
      const int orow = (wo << 6) + (f << 4) + lo;                             \
      FW[f] = ld_frag(B_ + (orow << 2) + (hi ^ ((orow >> 1) & 3)));           \
    }                                                                         \
    __builtin_amdgcn_s_setprio(1);                                            \
    _Pragma("unroll")                                                         \
    for (int fo = 0; fo < 4; ++fo) {                                          \
      acc[fo][0] = __builtin_amdgcn_mfma_f32_16x16x32_bf16(                   \
          FW[fo], S0, acc[fo][0], 0, 0, 0);                                   \
      acc[fo][1] = __builtin_amdgcn_mfma_f32_16x16x32_bf16(                   \
          FW[fo], S1, acc[fo][1], 0, 0, 0);                                   \
    }                                                                         \
    __builtin_amdgcn_s_setprio(0);                                            \
  } while (0)

  bf16x8 FPa0, FPa1, FPb0, FPb1;

  // prologue: B0, A0, B1 in flight (order matters for vmcnt accounting)
  STAGE_B(0);
  LOADA(FPa0, FPa1, 0);
  STAGE_B(1);

#pragma unroll 2
  for (int kk = 0; kk < NSTEP - 2; kk += 2) {
    // -- half-step kk: compute with FPa, load FPb(kk+1), stage B(kk+2)
    LOADA(FPb0, FPb1, kk + 1);
    STAGE_B(kk + 2);
    asm volatile("s_waitcnt vmcnt(6)" ::: "memory");   // B(kk) landed in LDS
    __builtin_amdgcn_s_barrier();
    asm volatile("" ::: "memory");
    DO_MMA(kk & 3, FPa0, FPa1);
    asm volatile("s_waitcnt lgkmcnt(0)" ::: "memory"); // FW reads drained

    // -- half-step kk+1: compute with FPb, load FPa(kk+2), stage B(kk+3)
    LOADA(FPa0, FPa1, kk + 2);
    STAGE_B(kk + 3);
    asm volatile("s_waitcnt vmcnt(6)" ::: "memory");   // B(kk+1) landed
    __builtin_amdgcn_s_barrier();
    asm volatile("" ::: "memory");
    DO_MMA((kk + 1) & 3, FPb0, FPb1);
    asm volatile("s_waitcnt lgkmcnt(0)" ::: "memory");
  }

  // tail: steps 34 (FPa holds A34), 35
  LOADA(FPb0, FPb1, NSTEP - 1);
  asm volatile("s_waitcnt vmcnt(3)" ::: "memory");     // B(34)+A(34) landed
  __builtin_amdgcn_s_barrier();
  asm volatile("" ::: "memory");
  DO_MMA(2, FPa0, FPa1);
  asm volatile("s_waitcnt lgkmcnt(0)" ::: "memory");

  asm volatile("s_waitcnt vmcnt(0)" ::: "memory");     // B(35)+A(35) landed
  __builtin_amdgcn_s_barrier();
  asm volatile("" ::: "memory");
  DO_MMA(3, FPb0, FPb1);
#undef TOFF
#undef LOADA
#undef STAGE_B
#undef DO_MMA

  // ---- epilogue: D row = o (hi*4+j), col = pix (lo); +bias
  float* ob = out + ((size_t)b << 18) + ((size_t)ohalf << 17) + (y0 << 5);
#pragma unroll
  for (int fo = 0; fo < 4; ++fo) {
    const int obase = (wo << 6) + (fo << 4) + (hi << 2);
#pragma unroll
    for (int fp = 0; fp < 2; ++fp) {
      const int pix = (wp << 5) + (fp << 4) + lo;
#pragma unroll
      for (int j = 0; j < 4; ++j) {
        const int o = obase + j;
        ob[((size_t)o << 10) + pix] = acc[fo][fp][j] + bias_s[o];
      }
    }
  }
}

// ------------------- exact fp32 fallback (ws too small) --------------------
__global__ __launch_bounds__(256) void sconv_naive(
    const float* __restrict__ in, const float* __restrict__ w,
    const float* __restrict__ bias, const int* __restrict__ selh,
    const int* __restrict__ selw, float* __restrict__ out) {
  int idx = (blockIdx.x << 8) + threadIdx.x;
  if (idx >= 32 * 256 * 32 * 32) return;
  int x = idx & 31, y = (idx >> 5) & 31, o = (idx >> 10) & 255, b = idx >> 18;
  int rh0 = 2 * y + selh[(y << 5) | x] - 1;
  int rw0 = 2 * x + selw[(y << 5) | x] - 1;
  const float* inb = in + ((size_t)b << 19);
  const float* wo_ = w + o * 1152;
  float acc = bias[o];
  for (int c = 0; c < 128; ++c)
    for (int i = 0; i < 3; ++i) {
      int rh = rh0 + i;
      if (rh < 0 || rh >= 64) continue;
      for (int j = 0; j < 3; ++j) {
        int rw = rw0 + j;
        if (rw < 0 || rw >= 64) continue;
        acc += inb[(c << 12) + (rh << 6) + rw] * wo_[c * 9 + i * 3 + j];
      }
    }
  out[idx] = acc;
}

extern "C" void kernel_launch(void* const* d_in, const int* in_sizes, int n_in,
                              void* d_out, int out_size, void* d_ws, size_t ws_size,
                              hipStream_t stream) {
  const float* in   = (const float*)d_in[0];
  const float* w    = (const float*)d_in[1];
  const float* bias = (const float*)d_in[2];
  const int*   selh = (const int*)d_in[3];
  const int*   selw = (const int*)d_in[4];
  float* out = (float*)d_out;

  if (ws_size >= (size_t)TOTAL_WS) {
    unsigned short* wpre = (unsigned short*)d_ws;
    unsigned short* tp   = (unsigned short*)((char*)d_ws + WPRE_BYTES);
    prep<<<dim3(102, 32), dim3(256), 0, stream>>>(in, w, tp, wpre);
    sconv_mfma6<<<dim3(512), dim3(512), 0, stream>>>(tp, wpre, bias, selh, selw, out);
  } else {
    sconv_naive<<<dim3(32768), dim3(256), 0, stream>>>(in, w, bias, selh, selw, out);
  }
}